// Round 4
// baseline (376.263 us; speedup 1.0000x reference)
//
#include <hip/hip_runtime.h>
#include <hip/hip_bf16.h>
#include <stdint.h>

typedef unsigned short u16;
typedef __attribute__((ext_vector_type(4))) float f32x4;
typedef __attribute__((ext_vector_type(8))) short bf16x8;
typedef __attribute__((ext_vector_type(4))) unsigned int u32x4;

#define GLL16(src, dst) __builtin_amdgcn_global_load_lds( \
    (const __attribute__((address_space(1))) void*)(src), \
    (__attribute__((address_space(3))) void*)(dst), 16, 0, 0)

static __device__ __forceinline__ u16 f2bf(float x) {
    uint32_t u = __builtin_bit_cast(uint32_t, x);
    u += 0x7fffu + ((u >> 16) & 1u);
    return (u16)(u >> 16);
}

static __device__ __forceinline__ uint32_t cvtpk(float lo, float hi) {
    uint32_t r;
    asm("v_cvt_pk_bf16_f32 %0, %1, %2" : "=v"(r) : "v"(lo), "v"(hi));
    return r;
}

// ---------------- fp32 -> bf16 conversion (vectorized) ----------------
__global__ __launch_bounds__(256) void cvt_f32_bf16(
        const float* __restrict__ in, u16* __restrict__ out, int n4) {
    int i = blockIdx.x * 256 + threadIdx.x;
    if (i >= n4) return;
    float4 v = ((const float4*)in)[i];
    ushort4 o;
    o.x = f2bf(v.x); o.y = f2bf(v.y); o.z = f2bf(v.z); o.w = f2bf(v.w);
    ((ushort4*)out)[i] = o;
}

// ---------------- mask -> additive bias (0 or -1e12) ----------------
__global__ __launch_bounds__(256) void mask_bias(
        const float* __restrict__ m, float* __restrict__ mb, int n) {
    int i = blockIdx.x * 256 + threadIdx.x;
    if (i < n) mb[i] = (m[i] != 0.f) ? 0.f : -1e12f;
}

// ---------------- GEMM: C[m,n] = sum_k A[m,k]*Bt[n,k] + bias[n] ----------------
// 128x128 tile, BK=32, 256 threads (4 waves 2x2, 64x64 each), mfma 16x16x32 bf16.
// MODE 0: bf16 out row-major [M,N]
// MODE 1: bf16 out scattered to Vt[(b*16+h)*64+d][s'] with s permuted within
//         each 64-block: orig (i,l4,r) -> s' = (i>>1)*32 + l4*8 + (i&1)*4 + r.
//         This makes attn's PV B-operand == lane-local P quads (no P shuffle).
// MODE 2: fp32 out row-major [M,N]
template <int MODE>
__global__ __launch_bounds__(256, 2) void gemm_bt(
        const u16* __restrict__ A, const u16* __restrict__ Bt,
        const float* __restrict__ bias, void* __restrict__ outp,
        int M, int N, int K) {
    __shared__ __align__(16) u16 As[128 * 32];
    __shared__ __align__(16) u16 Bs[128 * 32];
    const int tid = threadIdx.x;
    const int lane = tid & 63;
    const int w = tid >> 6, wm = w >> 1, wn = w & 1;
    const int l15 = lane & 15, l4 = lane >> 4;
    const int m0 = blockIdx.y * 128, n0 = blockIdx.x * 128;

    f32x4 acc[4][4];
#pragma unroll
    for (int i = 0; i < 4; i++)
#pragma unroll
        for (int j = 0; j < 4; j++) acc[i][j] = f32x4{0.f, 0.f, 0.f, 0.f};

    for (int kt = 0; kt < K; kt += 32) {
        __syncthreads();
#pragma unroll
        for (int i = 0; i < 2; i++) {
            int c = tid + i * 256;
            int row = c >> 2, slot = c & 3;
            int cc = slot ^ ((row >> 1) & 3);
            GLL16(A + (size_t)(m0 + row) * K + kt + cc * 8, As + c * 8);
        }
#pragma unroll
        for (int i = 0; i < 2; i++) {
            int c = tid + i * 256;
            int row = c >> 2, slot = c & 3;
            int cc = slot ^ ((row >> 1) & 3);
            GLL16(Bt + (size_t)(n0 + row) * K + kt + cc * 8, Bs + c * 8);
        }
        __syncthreads();

        bf16x8 af[4], bfr[4];
#pragma unroll
        for (int i = 0; i < 4; i++) {
            int row = wm * 64 + i * 16 + l15;
            int slot = l4 ^ ((row >> 1) & 3);
            af[i] = *(const bf16x8*)(As + row * 32 + slot * 8);
        }
#pragma unroll
        for (int j = 0; j < 4; j++) {
            int row = wn * 64 + j * 16 + l15;
            int slot = l4 ^ ((row >> 1) & 3);
            bfr[j] = *(const bf16x8*)(Bs + row * 32 + slot * 8);
        }
#pragma unroll
        for (int i = 0; i < 4; i++)
#pragma unroll
            for (int j = 0; j < 4; j++)
                acc[i][j] = __builtin_amdgcn_mfma_f32_16x16x32_bf16(af[i], bfr[j], acc[i][j], 0, 0, 0);
    }

#pragma unroll
    for (int j = 0; j < 4; j++) {
        int col = n0 + wn * 64 + j * 16 + l15;
        float bv = bias[col];
#pragma unroll
        for (int i = 0; i < 4; i++) {
            int rowb = m0 + wm * 64 + i * 16 + l4 * 4;
            if (MODE == 0) {
                u16* out = (u16*)outp;
#pragma unroll
                for (int r = 0; r < 4; r++)
                    out[(size_t)(rowb + r) * N + col] = f2bf(acc[i][j][r] + bv);
            } else if (MODE == 1) {
                u16* out = (u16*)outp;
                int bb = rowb >> 11;
                // permuted s within the 64-block (see header comment)
                int sp = ((m0 + wm * 64) & 2047) + (i >> 1) * 32 + l4 * 8 + (i & 1) * 4;
                int hh = col >> 6, dd = col & 63;
                ushort4 o;
                o.x = f2bf(acc[i][j][0] + bv);
                o.y = f2bf(acc[i][j][1] + bv);
                o.z = f2bf(acc[i][j][2] + bv);
                o.w = f2bf(acc[i][j][3] + bv);
                *(ushort4*)(out + ((size_t)((bb * 16 + hh) * 64 + dd)) * 2048 + sp) = o;
            } else {
                float* out = (float*)outp;
#pragma unroll
                for (int r = 0; r < 4; r++)
                    out[(size_t)(rowb + r) * N + col] = acc[i][j][r] + bv;
            }
        }
    }
}

// ---------------- fused flash attention ----------------
// grid (S/128, B*NH). 256 threads = 4 waves, each wave owns 32 q-rows.
// S^T = mfma(K_frag, Q_frag): lane holds q=l15 col, kv quads in regs.
// V is s-permuted in global memory so PV's B-operand (8 kv per lane at
// kf*32+l4*8+e) == the lane's own P quads {2kf,2kf+1} -> pb is pure register
// packing via cvt_pk; NO P LDS round-trip, NO cross-lane ops.
// K/V double-buffered (32 KB LDS total), one barrier/iter.
__global__ __launch_bounds__(256, 4) void attn_fused(
        const u16* __restrict__ Q, const u16* __restrict__ K,
        const u16* __restrict__ Vt, const float* __restrict__ mask,
        const float* __restrict__ mbias, u16* __restrict__ ctx) {
    __shared__ __align__(16) u16 Ks[2][64 * 64];    // [kv][d], swizzled slots
    __shared__ __align__(16) u16 Vs[2][64 * 64];    // [d][s'], swizzled slots

    const int tid = threadIdx.x, lane = tid & 63, w = tid >> 6;
    const int l15 = lane & 15, l4 = lane >> 4;
    const int bh = blockIdx.y, b = bh >> 4, h = bh & 15;
    const int qw = blockIdx.x * 128 + w * 32;
    const float SC2 = 0.03125f * 1.44269504088896f;  // (1/sqrt(1024)) * log2(e)
    const float THR2 = 8.0f;

    const u16* Qg = Q + (size_t)b * 2048 * 1024 + h * 64;
    const u16* Kg = K + (size_t)b * 2048 * 1024 + h * 64;
    const u16* Vg = Vt + (size_t)bh * 64 * 2048;
    const float* mp = mask + b * 2048;
    const float* mbp = mbias + b * 2048;

#define STAGE_KV(buf, kvbase) do {                                         \
    _Pragma("unroll")                                                      \
    for (int i_ = 0; i_ < 2; i_++) {                                       \
        int c_ = tid + i_ * 256;                                           \
        int row_ = c_ >> 3, slot_ = c_ & 7;                                \
        int cc_ = slot_ ^ (row_ & 7);                                      \
        GLL16(Kg + (size_t)((kvbase) + row_) * 1024 + cc_ * 8, Ks[buf] + c_ * 8); \
    }                                                                      \
    _Pragma("unroll")                                                      \
    for (int i_ = 0; i_ < 2; i_++) {                                       \
        int c_ = tid + i_ * 256;                                           \
        int row_ = c_ >> 3, slot_ = c_ & 7;                                \
        int cc_ = slot_ ^ (row_ & 7);                                      \
        GLL16(Vg + (size_t)row_ * 2048 + (kvbase) + cc_ * 8, Vs[buf] + c_ * 8); \
    }                                                                      \
} while (0)

    // hoist Q fragments (B-operand layout)
    bf16x8 qfr[2][2];
#pragma unroll
    for (int qi = 0; qi < 2; qi++)
#pragma unroll
        for (int kf = 0; kf < 2; kf++)
            qfr[qi][kf] = *(const bf16x8*)(Qg + (size_t)(qw + qi * 16 + l15) * 1024 + kf * 32 + l4 * 8);

    // q-mask handling, hoisted: masked q => s2 forced to 0 (uniform softmax)
    float mqs[2], qfl[2];
#pragma unroll
    for (int qi = 0; qi < 2; qi++) {
        float mq = mp[qw + qi * 16 + l15];
        mqs[qi] = (mq != 0.f) ? SC2 : 0.f;
        qfl[qi] = (mq != 0.f) ? -__builtin_inff() : 0.f;
    }

    float m_run[2], l_run[2];
    f32x4 oaccT[4][2];   // O^T: [d-frag][q-frag], row=d=l4*4+reg, col=q=l15
#pragma unroll
    for (int qi = 0; qi < 2; qi++) { m_run[qi] = -__builtin_inff(); l_run[qi] = 0.f; }
#pragma unroll
    for (int df = 0; df < 4; df++)
#pragma unroll
        for (int qi = 0; qi < 2; qi++) oaccT[df][qi] = f32x4{0.f, 0.f, 0.f, 0.f};

    STAGE_KV(0, 0);
    __syncthreads();

    for (int it = 0; it < 32; ++it) {
        const int cur = it & 1;
        const int kv0 = it * 64;

        // key-side additive bias for THIS tile (true-kv order, matches QK^T C-layout)
        float4 kb[4];
#pragma unroll
        for (int kvf = 0; kvf < 4; kvf++)
            kb[kvf] = ((const float4*)(mbp + kv0))[kvf * 4 + l4];

        if (it != 31) STAGE_KV(cur ^ 1, kv0 + 64);

        // ---- S^T = K Q^T ----
        bf16x8 kfr[4][2];
#pragma unroll
        for (int kvf = 0; kvf < 4; kvf++)
#pragma unroll
            for (int kf = 0; kf < 2; kf++) {
                int row = kvf * 16 + l15;
                int slot = (kf * 4 + l4) ^ (row & 7);
                kfr[kvf][kf] = *(const bf16x8*)(Ks[cur] + row * 64 + slot * 8);
            }
        f32x4 p[4][2];
#pragma unroll
        for (int kvf = 0; kvf < 4; kvf++)
#pragma unroll
            for (int qi = 0; qi < 2; qi++) p[kvf][qi] = f32x4{0.f, 0.f, 0.f, 0.f};
        __builtin_amdgcn_s_setprio(1);
#pragma unroll
        for (int kvf = 0; kvf < 4; kvf++)
#pragma unroll
            for (int qi = 0; qi < 2; qi++)
#pragma unroll
                for (int kf = 0; kf < 2; kf++)
                    p[kvf][qi] = __builtin_amdgcn_mfma_f32_16x16x32_bf16(kfr[kvf][kf], qfr[qi][kf], p[kvf][qi], 0, 0, 0);
        __builtin_amdgcn_s_setprio(0);

        // V fragments issued early: ds_read latency hides under softmax VALU
        bf16x8 vfr[4][2];
#pragma unroll
        for (int df = 0; df < 4; df++)
#pragma unroll
            for (int kf = 0; kf < 2; kf++) {
                int row = df * 16 + l15;
                int slot = (kf * 4 + l4) ^ (row & 7);
                vfr[df][kf] = *(const bf16x8*)(Vs[cur] + row * 64 + slot * 8);
            }

        // ---- base-2 online softmax ----
        float pm[2];
#pragma unroll
        for (int qi = 0; qi < 2; qi++) {
#pragma unroll
            for (int kvf = 0; kvf < 4; kvf++)
#pragma unroll
                for (int r = 0; r < 4; r++) {
                    float s2 = __builtin_fmaf(p[kvf][qi][r], mqs[qi], kb[kvf][r]);
                    s2 = fmaxf(s2, qfl[qi]);
                    p[kvf][qi][r] = s2;
                }
            float a0 = fmaxf(fmaxf(p[0][qi][0], p[0][qi][1]), fmaxf(p[0][qi][2], p[0][qi][3]));
            float a1 = fmaxf(fmaxf(p[1][qi][0], p[1][qi][1]), fmaxf(p[1][qi][2], p[1][qi][3]));
            float a2 = fmaxf(fmaxf(p[2][qi][0], p[2][qi][1]), fmaxf(p[2][qi][2], p[2][qi][3]));
            float a3 = fmaxf(fmaxf(p[3][qi][0], p[3][qi][1]), fmaxf(p[3][qi][2], p[3][qi][3]));
            float t = fmaxf(fmaxf(a0, a1), fmaxf(a2, a3));
            t = fmaxf(t, __shfl_xor(t, 16));
            t = fmaxf(t, __shfl_xor(t, 32));
            pm[qi] = t;
        }
        // defer-max: skip rescale when tile max grew by < THR2 (base-2 units)
        if (!__all((pm[0] <= m_run[0] + THR2) && (pm[1] <= m_run[1] + THR2))) {
#pragma unroll
            for (int qi = 0; qi < 2; qi++) {
                float mn = fmaxf(m_run[qi], pm[qi]);
                float sc = __builtin_amdgcn_exp2f(m_run[qi] - mn);
                m_run[qi] = mn;
                l_run[qi] *= sc;
#pragma unroll
                for (int df = 0; df < 4; df++) oaccT[df][qi] *= sc;
            }
        }
#pragma unroll
        for (int qi = 0; qi < 2; qi++) {
            float rs = 0.f;
#pragma unroll
            for (int kvf = 0; kvf < 4; kvf++)
#pragma unroll
                for (int r = 0; r < 4; r++) {
                    float ev = __builtin_amdgcn_exp2f(p[kvf][qi][r] - m_run[qi]);
                    p[kvf][qi][r] = ev;
                    rs += ev;
                }
            rs += __shfl_xor(rs, 16);
            rs += __shfl_xor(rs, 32);
            l_run[qi] += rs;
        }

        // ---- pb = lane-local P quads packed to bf16 (V s-permutation makes
        //      element e of pb[qi][kf] == true kv = kf*32+(e>>2)*16+l4*4+(e&3))
        bf16x8 pb[2][2];
#pragma unroll
        for (int qi = 0; qi < 2; qi++)
#pragma unroll
            for (int kf = 0; kf < 2; kf++) {
                u32x4 t;
                t.x = cvtpk(p[2 * kf][qi][0], p[2 * kf][qi][1]);
                t.y = cvtpk(p[2 * kf][qi][2], p[2 * kf][qi][3]);
                t.z = cvtpk(p[2 * kf + 1][qi][0], p[2 * kf + 1][qi][1]);
                t.w = cvtpk(p[2 * kf + 1][qi][2], p[2 * kf + 1][qi][3]);
                pb[qi][kf] = __builtin_bit_cast(bf16x8, t);
            }

        // ---- O^T += V^T P^T ----
        __builtin_amdgcn_s_setprio(1);
#pragma unroll
        for (int df = 0; df < 4; df++)
#pragma unroll
            for (int qi = 0; qi < 2; qi++)
#pragma unroll
                for (int kf = 0; kf < 2; kf++)
                    oaccT[df][qi] = __builtin_amdgcn_mfma_f32_16x16x32_bf16(vfr[df][kf], pb[qi][kf], oaccT[df][qi], 0, 0, 0);
        __builtin_amdgcn_s_setprio(0);

        __syncthreads();   // drains prefetch vmcnt + protects both dbuf halves
    }

    // ---- epilogue: ctx[token][h*64+d] = O^T / l ----
#pragma unroll
    for (int qi = 0; qi < 2; qi++) {
        float rl = 1.0f / l_run[qi];
        int tok = qw + qi * 16 + l15;
#pragma unroll
        for (int df = 0; df < 4; df++) {
            uint2 o;
            o.x = cvtpk(oaccT[df][qi][0] * rl, oaccT[df][qi][1] * rl);
            o.y = cvtpk(oaccT[df][qi][2] * rl, oaccT[df][qi][3] * rl);
            *(uint2*)(ctx + (size_t)(b * 2048 + tok) * 1024 + h * 64 + df * 16 + l4 * 4) = o;
        }
    }
#undef STAGE_KV
}

extern "C" void kernel_launch(void* const* d_in, const int* in_sizes, int n_in,
                              void* d_out, int out_size, void* d_ws, size_t ws_size,
                              hipStream_t stream) {
    const float* hs    = (const float*)d_in[0];
    const float* masks = (const float*)d_in[1];
    const float* Wq = (const float*)d_in[2];
    const float* bq = (const float*)d_in[3];
    const float* Wk = (const float*)d_in[4];
    const float* bk = (const float*)d_in[5];
    const float* Wv = (const float*)d_in[6];
    const float* bv = (const float*)d_in[7];
    const float* Wo = (const float*)d_in[8];
    const float* bo = (const float*)d_in[9];

    const int NT = 4 * 2048;   // 8192 tokens
    const int H = 1024;

    u16* hs_b = (u16*)d_ws;
    u16* wq_b = hs_b + (size_t)NT * H;
    u16* wk_b = wq_b + (size_t)H * H;
    u16* wv_b = wk_b + (size_t)H * H;
    u16* wo_b = wv_b + (size_t)H * H;
    u16* Qb   = wo_b + (size_t)H * H;
    u16* Kb   = Qb + (size_t)NT * H;
    u16* Vtb  = Kb + (size_t)NT * H;
    u16* Cb   = hs_b;
    // mask-bias overlays wq_b's region (dead after the Q GEMM)
    float* mb = (float*)wq_b;

    cvt_f32_bf16<<<NT * H / 1024, 256, 0, stream>>>(hs, hs_b, NT * H / 4);
    cvt_f32_bf16<<<H * H / 1024, 256, 0, stream>>>(Wq, wq_b, H * H / 4);
    cvt_f32_bf16<<<H * H / 1024, 256, 0, stream>>>(Wk, wk_b, H * H / 4);
    cvt_f32_bf16<<<H * H / 1024, 256, 0, stream>>>(Wv, wv_b, H * H / 4);
    cvt_f32_bf16<<<H * H / 1024, 256, 0, stream>>>(Wo, wo_b, H * H / 4);

    dim3 gg(H / 128, NT / 128);   // (8, 64)
    gemm_bt<0><<<gg, 256, 0, stream>>>(hs_b, wq_b, bq, Qb,  NT, H, H);
    gemm_bt<0><<<gg, 256, 0, stream>>>(hs_b, wk_b, bk, Kb,  NT, H, H);
    gemm_bt<1><<<gg, 256, 0, stream>>>(hs_b, wv_b, bv, Vtb, NT, H, H);

    mask_bias<<<(4 * 2048 + 255) / 256, 256, 0, stream>>>(masks, mb, 4 * 2048);

    attn_fused<<<dim3(2048 / 128, 64), 256, 0, stream>>>(Qb, Kb, Vtb, masks, mb, Cb);

    gemm_bt<2><<<gg, 256, 0, stream>>>(Cb, wo_b, bo, d_out, NT, H, H);
}

// Round 5
// 249.518 us; speedup vs baseline: 1.5080x; 1.5080x over previous
//
#include <hip/hip_runtime.h>
#include <hip/hip_bf16.h>
#include <stdint.h>

typedef unsigned short u16;
typedef __attribute__((ext_vector_type(4))) float f32x4;
typedef __attribute__((ext_vector_type(8))) short bf16x8;
typedef __attribute__((ext_vector_type(4))) unsigned int u32x4;

#define GLL16(src, dst) __builtin_amdgcn_global_load_lds( \
    (const __attribute__((address_space(1))) void*)(src), \
    (__attribute__((address_space(3))) void*)(dst), 16, 0, 0)

static __device__ __forceinline__ u16 f2bf(float x) {
    uint32_t u = __builtin_bit_cast(uint32_t, x);
    u += 0x7fffu + ((u >> 16) & 1u);
    return (u16)(u >> 16);
}

static __device__ __forceinline__ uint32_t cvtpk(float lo, float hi) {
    uint32_t r;
    asm("v_cvt_pk_bf16_f32 %0, %1, %2" : "=v"(r) : "v"(lo), "v"(hi));
    return r;
}

// ---------------- fp32 -> bf16 conversion (vectorized) ----------------
__global__ __launch_bounds__(256) void cvt_f32_bf16(
        const float* __restrict__ in, u16* __restrict__ out, int n4) {
    int i = blockIdx.x * 256 + threadIdx.x;
    if (i >= n4) return;
    float4 v = ((const float4*)in)[i];
    ushort4 o;
    o.x = f2bf(v.x); o.y = f2bf(v.y); o.z = f2bf(v.z); o.w = f2bf(v.w);
    ((ushort4*)out)[i] = o;
}

// ---------------- mask -> additive bias (0 or -1e12) ----------------
__global__ __launch_bounds__(256) void mask_bias(
        const float* __restrict__ m, float* __restrict__ mb, int n) {
    int i = blockIdx.x * 256 + threadIdx.x;
    if (i < n) mb[i] = (m[i] != 0.f) ? 0.f : -1e12f;
}

// ---------------- GEMM: C[m,n] = sum_k A[m,k]*Bt[n,k] + bias[n] ----------------
// 128x128 tile, BK=32, 256 threads (4 waves 2x2, 64x64 each), mfma 16x16x32 bf16.
// MODE 0: bf16 out row-major [M,N]
// MODE 1: bf16 out scattered to Vt[(b*16+h)*64+d][s'] with s permuted within
//         each 64-block: orig (i,l4,r) -> s' = (i>>1)*32 + l4*8 + (i&1)*4 + r.
//         This makes attn's PV B-operand == lane-local P quads (no P shuffle).
// MODE 2: fp32 out row-major [M,N]
template <int MODE>
__global__ __launch_bounds__(256, 2) void gemm_bt(
        const u16* __restrict__ A, const u16* __restrict__ Bt,
        const float* __restrict__ bias, void* __restrict__ outp,
        int M, int N, int K) {
    __shared__ __align__(16) u16 As[128 * 32];
    __shared__ __align__(16) u16 Bs[128 * 32];
    const int tid = threadIdx.x;
    const int lane = tid & 63;
    const int w = tid >> 6, wm = w >> 1, wn = w & 1;
    const int l15 = lane & 15, l4 = lane >> 4;
    const int m0 = blockIdx.y * 128, n0 = blockIdx.x * 128;

    f32x4 acc[4][4];
#pragma unroll
    for (int i = 0; i < 4; i++)
#pragma unroll
        for (int j = 0; j < 4; j++) acc[i][j] = f32x4{0.f, 0.f, 0.f, 0.f};

    for (int kt = 0; kt < K; kt += 32) {
        __syncthreads();
#pragma unroll
        for (int i = 0; i < 2; i++) {
            int c = tid + i * 256;
            int row = c >> 2, slot = c & 3;
            int cc = slot ^ ((row >> 1) & 3);
            GLL16(A + (size_t)(m0 + row) * K + kt + cc * 8, As + c * 8);
        }
#pragma unroll
        for (int i = 0; i < 2; i++) {
            int c = tid + i * 256;
            int row = c >> 2, slot = c & 3;
            int cc = slot ^ ((row >> 1) & 3);
            GLL16(Bt + (size_t)(n0 + row) * K + kt + cc * 8, Bs + c * 8);
        }
        __syncthreads();

        bf16x8 af[4], bfr[4];
#pragma unroll
        for (int i = 0; i < 4; i++) {
            int row = wm * 64 + i * 16 + l15;
            int slot = l4 ^ ((row >> 1) & 3);
            af[i] = *(const bf16x8*)(As + row * 32 + slot * 8);
        }
#pragma unroll
        for (int j = 0; j < 4; j++) {
            int row = wn * 64 + j * 16 + l15;
            int slot = l4 ^ ((row >> 1) & 3);
            bfr[j] = *(const bf16x8*)(Bs + row * 32 + slot * 8);
        }
#pragma unroll
        for (int i = 0; i < 4; i++)
#pragma unroll
            for (int j = 0; j < 4; j++)
                acc[i][j] = __builtin_amdgcn_mfma_f32_16x16x32_bf16(af[i], bfr[j], acc[i][j], 0, 0, 0);
    }

#pragma unroll
    for (int j = 0; j < 4; j++) {
        int col = n0 + wn * 64 + j * 16 + l15;
        float bv = bias[col];
#pragma unroll
        for (int i = 0; i < 4; i++) {
            int rowb = m0 + wm * 64 + i * 16 + l4 * 4;
            if (MODE == 0) {
                u16* out = (u16*)outp;
#pragma unroll
                for (int r = 0; r < 4; r++)
                    out[(size_t)(rowb + r) * N + col] = f2bf(acc[i][j][r] + bv);
            } else if (MODE == 1) {
                u16* out = (u16*)outp;
                int bb = rowb >> 11;
                // permuted s within the 64-block (see header comment)
                int sp = ((m0 + wm * 64) & 2047) + (i >> 1) * 32 + l4 * 8 + (i & 1) * 4;
                int hh = col >> 6, dd = col & 63;
                ushort4 o;
                o.x = f2bf(acc[i][j][0] + bv);
                o.y = f2bf(acc[i][j][1] + bv);
                o.z = f2bf(acc[i][j][2] + bv);
                o.w = f2bf(acc[i][j][3] + bv);
                *(ushort4*)(out + ((size_t)((bb * 16 + hh) * 64 + dd)) * 2048 + sp) = o;
            } else {
                float* out = (float*)outp;
#pragma unroll
                for (int r = 0; r < 4; r++)
                    out[(size_t)(rowb + r) * N + col] = acc[i][j][r] + bv;
            }
        }
    }
}

// ---------------- fused flash attention ----------------
// grid (S/128, B*NH). 256 threads = 4 waves, each wave owns 32 q-rows.
// S^T = mfma(K_frag, Q_frag): lane holds q=l15 col, kv quads in regs.
// V is s-permuted in global memory so PV's B-operand (8 kv per lane at
// kf*32+l4*8+e) == the lane's own P quads {2kf,2kf+1} -> pb is pure register
// packing via cvt_pk; NO P LDS round-trip, NO cross-lane ops.
// K/V double-buffered (32 KB LDS), one barrier/iter.
// launch_bounds(256,3): R4's (256,4) capped VGPR at 128 -> catastrophic
// scratch spill (384 MB writes/dispatch). vfr is loaded AFTER softmax so it
// is not live across the VALU phase.
__global__ __launch_bounds__(256, 3) void attn_fused(
        const u16* __restrict__ Q, const u16* __restrict__ K,
        const u16* __restrict__ Vt, const float* __restrict__ mask,
        const float* __restrict__ mbias, u16* __restrict__ ctx) {
    __shared__ __align__(16) u16 Ks[2][64 * 64];    // [kv][d], swizzled slots
    __shared__ __align__(16) u16 Vs[2][64 * 64];    // [d][s'], swizzled slots

    const int tid = threadIdx.x, lane = tid & 63, w = tid >> 6;
    const int l15 = lane & 15, l4 = lane >> 4;
    const int bh = blockIdx.y, b = bh >> 4, h = bh & 15;
    const int qw = blockIdx.x * 128 + w * 32;
    const float SC2 = 0.03125f * 1.44269504088896f;  // (1/sqrt(1024)) * log2(e)
    const float THR2 = 8.0f;

    const u16* Qg = Q + (size_t)b * 2048 * 1024 + h * 64;
    const u16* Kg = K + (size_t)b * 2048 * 1024 + h * 64;
    const u16* Vg = Vt + (size_t)bh * 64 * 2048;
    const float* mp = mask + b * 2048;
    const float* mbp = mbias + b * 2048;

#define STAGE_KV(buf, kvbase) do {                                         \
    _Pragma("unroll")                                                      \
    for (int i_ = 0; i_ < 2; i_++) {                                       \
        int c_ = tid + i_ * 256;                                           \
        int row_ = c_ >> 3, slot_ = c_ & 7;                                \
        int cc_ = slot_ ^ (row_ & 7);                                      \
        GLL16(Kg + (size_t)((kvbase) + row_) * 1024 + cc_ * 8, Ks[buf] + c_ * 8); \
    }                                                                      \
    _Pragma("unroll")                                                      \
    for (int i_ = 0; i_ < 2; i_++) {                                       \
        int c_ = tid + i_ * 256;                                           \
        int row_ = c_ >> 3, slot_ = c_ & 7;                                \
        int cc_ = slot_ ^ (row_ & 7);                                      \
        GLL16(Vg + (size_t)row_ * 2048 + (kvbase) + cc_ * 8, Vs[buf] + c_ * 8); \
    }                                                                      \
} while (0)

    // hoist Q fragments (B-operand layout)
    bf16x8 qfr[2][2];
#pragma unroll
    for (int qi = 0; qi < 2; qi++)
#pragma unroll
        for (int kf = 0; kf < 2; kf++)
            qfr[qi][kf] = *(const bf16x8*)(Qg + (size_t)(qw + qi * 16 + l15) * 1024 + kf * 32 + l4 * 8);

    // q-mask handling, hoisted: masked q => s2 forced to 0 (uniform softmax)
    float mqs[2], qfl[2];
#pragma unroll
    for (int qi = 0; qi < 2; qi++) {
        float mq = mp[qw + qi * 16 + l15];
        mqs[qi] = (mq != 0.f) ? SC2 : 0.f;
        qfl[qi] = (mq != 0.f) ? -__builtin_inff() : 0.f;
    }

    float m_run[2], l_run[2];
    f32x4 oaccT[4][2];   // O^T: [d-frag][q-frag], row=d=l4*4+reg, col=q=l15
#pragma unroll
    for (int qi = 0; qi < 2; qi++) { m_run[qi] = -__builtin_inff(); l_run[qi] = 0.f; }
#pragma unroll
    for (int df = 0; df < 4; df++)
#pragma unroll
        for (int qi = 0; qi < 2; qi++) oaccT[df][qi] = f32x4{0.f, 0.f, 0.f, 0.f};

    STAGE_KV(0, 0);
    __syncthreads();

    for (int it = 0; it < 32; ++it) {
        const int cur = it & 1;
        const int kv0 = it * 64;

        // key-side additive bias for THIS tile (true-kv order, matches QK^T C-layout)
        float4 kb[4];
#pragma unroll
        for (int kvf = 0; kvf < 4; kvf++)
            kb[kvf] = ((const float4*)(mbp + kv0))[kvf * 4 + l4];

        if (it != 31) STAGE_KV(cur ^ 1, kv0 + 64);

        // ---- S^T = K Q^T ----
        bf16x8 kfr[4][2];
#pragma unroll
        for (int kvf = 0; kvf < 4; kvf++)
#pragma unroll
            for (int kf = 0; kf < 2; kf++) {
                int row = kvf * 16 + l15;
                int slot = (kf * 4 + l4) ^ (row & 7);
                kfr[kvf][kf] = *(const bf16x8*)(Ks[cur] + row * 64 + slot * 8);
            }
        f32x4 p[4][2];
#pragma unroll
        for (int kvf = 0; kvf < 4; kvf++)
#pragma unroll
            for (int qi = 0; qi < 2; qi++) p[kvf][qi] = f32x4{0.f, 0.f, 0.f, 0.f};
        __builtin_amdgcn_s_setprio(1);
#pragma unroll
        for (int kvf = 0; kvf < 4; kvf++)
#pragma unroll
            for (int qi = 0; qi < 2; qi++)
#pragma unroll
                for (int kf = 0; kf < 2; kf++)
                    p[kvf][qi] = __builtin_amdgcn_mfma_f32_16x16x32_bf16(kfr[kvf][kf], qfr[qi][kf], p[kvf][qi], 0, 0, 0);
        __builtin_amdgcn_s_setprio(0);

        // ---- base-2 online softmax ----
        float pm[2];
#pragma unroll
        for (int qi = 0; qi < 2; qi++) {
#pragma unroll
            for (int kvf = 0; kvf < 4; kvf++)
#pragma unroll
                for (int r = 0; r < 4; r++) {
                    float s2 = __builtin_fmaf(p[kvf][qi][r], mqs[qi], kb[kvf][r]);
                    s2 = fmaxf(s2, qfl[qi]);
                    p[kvf][qi][r] = s2;
                }
            float a0 = fmaxf(fmaxf(p[0][qi][0], p[0][qi][1]), fmaxf(p[0][qi][2], p[0][qi][3]));
            float a1 = fmaxf(fmaxf(p[1][qi][0], p[1][qi][1]), fmaxf(p[1][qi][2], p[1][qi][3]));
            float a2 = fmaxf(fmaxf(p[2][qi][0], p[2][qi][1]), fmaxf(p[2][qi][2], p[2][qi][3]));
            float a3 = fmaxf(fmaxf(p[3][qi][0], p[3][qi][1]), fmaxf(p[3][qi][2], p[3][qi][3]));
            float t = fmaxf(fmaxf(a0, a1), fmaxf(a2, a3));
            t = fmaxf(t, __shfl_xor(t, 16));
            t = fmaxf(t, __shfl_xor(t, 32));
            pm[qi] = t;
        }
        // defer-max: skip rescale when tile max grew by < THR2 (base-2 units)
        if (!__all((pm[0] <= m_run[0] + THR2) && (pm[1] <= m_run[1] + THR2))) {
#pragma unroll
            for (int qi = 0; qi < 2; qi++) {
                float mn = fmaxf(m_run[qi], pm[qi]);
                float sc = __builtin_amdgcn_exp2f(m_run[qi] - mn);
                m_run[qi] = mn;
                l_run[qi] *= sc;
#pragma unroll
                for (int df = 0; df < 4; df++) oaccT[df][qi] *= sc;
            }
        }
#pragma unroll
        for (int qi = 0; qi < 2; qi++) {
            float rs = 0.f;
#pragma unroll
            for (int kvf = 0; kvf < 4; kvf++)
#pragma unroll
                for (int r = 0; r < 4; r++) {
                    float ev = __builtin_amdgcn_exp2f(p[kvf][qi][r] - m_run[qi]);
                    p[kvf][qi][r] = ev;
                    rs += ev;
                }
            rs += __shfl_xor(rs, 16);
            rs += __shfl_xor(rs, 32);
            l_run[qi] += rs;
        }

        // ---- pb = lane-local P quads packed to bf16 (V s-permutation makes
        //      element e of pb[qi][kf] == true kv = kf*32+(e>>2)*16+l4*4+(e&3))
        bf16x8 pb[2][2];
#pragma unroll
        for (int qi = 0; qi < 2; qi++)
#pragma unroll
            for (int kf = 0; kf < 2; kf++) {
                u32x4 t;
                t.x = cvtpk(p[2 * kf][qi][0], p[2 * kf][qi][1]);
                t.y = cvtpk(p[2 * kf][qi][2], p[2 * kf][qi][3]);
                t.z = cvtpk(p[2 * kf + 1][qi][0], p[2 * kf + 1][qi][1]);
                t.w = cvtpk(p[2 * kf + 1][qi][2], p[2 * kf + 1][qi][3]);
                pb[qi][kf] = __builtin_bit_cast(bf16x8, t);
            }

        // V fragments loaded here (not before softmax) to keep them out of the
        // softmax-phase live set — R4's spill lesson.
        bf16x8 vfr[4][2];
#pragma unroll
        for (int df = 0; df < 4; df++)
#pragma unroll
            for (int kf = 0; kf < 2; kf++) {
                int row = df * 16 + l15;
                int slot = (kf * 4 + l4) ^ (row & 7);
                vfr[df][kf] = *(const bf16x8*)(Vs[cur] + row * 64 + slot * 8);
            }

        // ---- O^T += V^T P^T ----
        __builtin_amdgcn_s_setprio(1);
#pragma unroll
        for (int df = 0; df < 4; df++)
#pragma unroll
            for (int qi = 0; qi < 2; qi++)
#pragma unroll
                for (int kf = 0; kf < 2; kf++)
                    oaccT[df][qi] = __builtin_amdgcn_mfma_f32_16x16x32_bf16(vfr[df][kf], pb[qi][kf], oaccT[df][qi], 0, 0, 0);
        __builtin_amdgcn_s_setprio(0);

        __syncthreads();   // drains prefetch vmcnt + protects both dbuf halves
    }

    // ---- epilogue: ctx[token][h*64+d] = O^T / l ----
#pragma unroll
    for (int qi = 0; qi < 2; qi++) {
        float rl = 1.0f / l_run[qi];
        int tok = qw + qi * 16 + l15;
#pragma unroll
        for (int df = 0; df < 4; df++) {
            uint2 o;
            o.x = cvtpk(oaccT[df][qi][0] * rl, oaccT[df][qi][1] * rl);
            o.y = cvtpk(oaccT[df][qi][2] * rl, oaccT[df][qi][3] * rl);
            *(uint2*)(ctx + (size_t)(b * 2048 + tok) * 1024 + h * 64 + df * 16 + l4 * 4) = o;
        }
    }
#undef STAGE_KV
}

extern "C" void kernel_launch(void* const* d_in, const int* in_sizes, int n_in,
                              void* d_out, int out_size, void* d_ws, size_t ws_size,
                              hipStream_t stream) {
    const float* hs    = (const float*)d_in[0];
    const float* masks = (const float*)d_in[1];
    const float* Wq = (const float*)d_in[2];
    const float* bq = (const float*)d_in[3];
    const float* Wk = (const float*)d_in[4];
    const float* bk = (const float*)d_in[5];
    const float* Wv = (const float*)d_in[6];
    const float* bv = (const float*)d_in[7];
    const float* Wo = (const float*)d_in[8];
    const float* bo = (const float*)d_in[9];

    const int NT = 4 * 2048;   // 8192 tokens
    const int H = 1024;

    u16* hs_b = (u16*)d_ws;
    u16* wq_b = hs_b + (size_t)NT * H;
    u16* wk_b = wq_b + (size_t)H * H;
    u16* wv_b = wk_b + (size_t)H * H;
    u16* wo_b = wv_b + (size_t)H * H;
    u16* Qb   = wo_b + (size_t)H * H;
    u16* Kb   = Qb + (size_t)NT * H;
    u16* Vtb  = Kb + (size_t)NT * H;
    u16* Cb   = hs_b;
    // mask-bias overlays wq_b's region (dead after the Q GEMM)
    float* mb = (float*)wq_b;

    cvt_f32_bf16<<<NT * H / 1024, 256, 0, stream>>>(hs, hs_b, NT * H / 4);
    cvt_f32_bf16<<<H * H / 1024, 256, 0, stream>>>(Wq, wq_b, H * H / 4);
    cvt_f32_bf16<<<H * H / 1024, 256, 0, stream>>>(Wk, wk_b, H * H / 4);
    cvt_f32_bf16<<<H * H / 1024, 256, 0, stream>>>(Wv, wv_b, H * H / 4);
    cvt_f32_bf16<<<H * H / 1024, 256, 0, stream>>>(Wo, wo_b, H * H / 4);

    dim3 gg(H / 128, NT / 128);   // (8, 64)
    gemm_bt<0><<<gg, 256, 0, stream>>>(hs_b, wq_b, bq, Qb,  NT, H, H);
    gemm_bt<0><<<gg, 256, 0, stream>>>(hs_b, wk_b, bk, Kb,  NT, H, H);
    gemm_bt<1><<<gg, 256, 0, stream>>>(hs_b, wv_b, bv, Vtb, NT, H, H);

    mask_bias<<<(4 * 2048 + 255) / 256, 256, 0, stream>>>(masks, mb, 4 * 2048);

    attn_fused<<<dim3(2048 / 128, 64), 256, 0, stream>>>(Qb, Kb, Vtb, masks, mb, Cb);

    gemm_bt<2><<<gg, 256, 0, stream>>>(Cb, wo_b, bo, d_out, NT, H, H);
}

// Round 6
// 202.407 us; speedup vs baseline: 1.8589x; 1.2328x over previous
//
#include <hip/hip_runtime.h>
#include <hip/hip_bf16.h>
#include <stdint.h>

typedef unsigned short u16;
typedef __attribute__((ext_vector_type(4))) float f32x4;
typedef __attribute__((ext_vector_type(8))) short bf16x8;
typedef __attribute__((ext_vector_type(4))) unsigned int u32x4;

#define GLL16(src, dst) __builtin_amdgcn_global_load_lds( \
    (const __attribute__((address_space(1))) void*)(src), \
    (__attribute__((address_space(3))) void*)(dst), 16, 0, 0)

static __device__ __forceinline__ u16 f2bf(float x) {
    uint32_t u = __builtin_bit_cast(uint32_t, x);
    u += 0x7fffu + ((u >> 16) & 1u);
    return (u16)(u >> 16);
}

static __device__ __forceinline__ uint32_t cvtpk(float lo, float hi) {
    uint32_t r;
    asm("v_cvt_pk_bf16_f32 %0, %1, %2" : "=v"(r) : "v"(lo), "v"(hi));
    return r;
}

// ---------------- fp32 -> bf16 conversion ----------------
__global__ __launch_bounds__(256) void cvt_f32_bf16(
        const float* __restrict__ in, u16* __restrict__ out, int n4) {
    int i = blockIdx.x * 256 + threadIdx.x;
    if (i >= n4) return;
    float4 v = ((const float4*)in)[i];
    ushort4 o;
    o.x = f2bf(v.x); o.y = f2bf(v.y); o.z = f2bf(v.z); o.w = f2bf(v.w);
    ((ushort4*)out)[i] = o;
}

// all four weight matrices in one dispatch; dst rows: [Wq | Wk | Wv | Wo]
__global__ __launch_bounds__(256) void cvt_w4(
        const float* __restrict__ s0, const float* __restrict__ s1,
        const float* __restrict__ s2, const float* __restrict__ s3,
        u16* __restrict__ dst) {
    int wsel = blockIdx.y;
    const float* s = (wsel == 0) ? s0 : (wsel == 1) ? s1 : (wsel == 2) ? s2 : s3;
    int i = blockIdx.x * 256 + threadIdx.x;   // grid.x = 1024 -> 262144 float4
    float4 v = ((const float4*)s)[i];
    ushort4 o;
    o.x = f2bf(v.x); o.y = f2bf(v.y); o.z = f2bf(v.z); o.w = f2bf(v.w);
    ((ushort4*)(dst + (size_t)wsel * 1024 * 1024))[i] = o;
}

// ---------------- fused QKV GEMM ----------------
// C[m,n] = sum_k A[m,k] * Wcat[n,k] + bias, M=8192, N=3072, K=1024.
// 128x128 tile, BK=32, double-buffered LDS staging (one barrier/iter),
// 1D grid 1536 with bijective XCD swizzle.
// cols [0,1024) -> Q row-major bf16; [1024,2048) -> K row-major bf16;
// [2048,3072) -> V scattered to Vt[(b*16+h)*64+d][s'] with s-permute
//   (i,l4,r) -> s' = (i>>1)*32 + l4*8 + (i&1)*4 + r  (PV B-operand layout).
__global__ __launch_bounds__(256, 2) void gemm_qkv(
        const u16* __restrict__ A, const u16* __restrict__ W,
        const float* __restrict__ bq, const float* __restrict__ bk,
        const float* __restrict__ bv,
        u16* __restrict__ Qo, u16* __restrict__ Ko, u16* __restrict__ Vo) {
    __shared__ __align__(16) u16 As[2][128 * 32];
    __shared__ __align__(16) u16 Bs[2][128 * 32];
    const int tid = threadIdx.x;
    const int lane = tid & 63;
    const int w = tid >> 6, wm = w >> 1, wn = w & 1;
    const int l15 = lane & 15, l4 = lane >> 4;
    // XCD swizzle: 1536 blocks, 192 contiguous per XCD
    int v = (blockIdx.x & 7) * 192 + (blockIdx.x >> 3);
    int vy = v / 24, vx = v - vy * 24;
    const int m0 = vy * 128, n0 = vx * 128;

    f32x4 acc[4][4];
#pragma unroll
    for (int i = 0; i < 4; i++)
#pragma unroll
        for (int j = 0; j < 4; j++) acc[i][j] = f32x4{0.f, 0.f, 0.f, 0.f};

#define QKV_STAGE(buf, kt) do {                                            \
    _Pragma("unroll")                                                      \
    for (int i_ = 0; i_ < 2; i_++) {                                       \
        int c_ = tid + i_ * 256;                                           \
        int row_ = c_ >> 2, slot_ = c_ & 3;                                \
        int cc_ = slot_ ^ ((row_ >> 1) & 3);                               \
        GLL16(A + (size_t)(m0 + row_) * 1024 + (kt) + cc_ * 8, As[buf] + c_ * 8); \
    }                                                                      \
    _Pragma("unroll")                                                      \
    for (int i_ = 0; i_ < 2; i_++) {                                       \
        int c_ = tid + i_ * 256;                                           \
        int row_ = c_ >> 2, slot_ = c_ & 3;                                \
        int cc_ = slot_ ^ ((row_ >> 1) & 3);                               \
        GLL16(W + (size_t)(n0 + row_) * 1024 + (kt) + cc_ * 8, Bs[buf] + c_ * 8); \
    }                                                                      \
} while (0)

    QKV_STAGE(0, 0);
    __syncthreads();

    for (int kt = 0; kt < 1024; kt += 32) {
        const int cur = (kt >> 5) & 1;
        if (kt != 992) QKV_STAGE(cur ^ 1, kt + 32);

        bf16x8 af[4], bfr[4];
#pragma unroll
        for (int i = 0; i < 4; i++) {
            int row = wm * 64 + i * 16 + l15;
            int slot = l4 ^ ((row >> 1) & 3);
            af[i] = *(const bf16x8*)(As[cur] + row * 32 + slot * 8);
        }
#pragma unroll
        for (int j = 0; j < 4; j++) {
            int row = wn * 64 + j * 16 + l15;
            int slot = l4 ^ ((row >> 1) & 3);
            bfr[j] = *(const bf16x8*)(Bs[cur] + row * 32 + slot * 8);
        }
#pragma unroll
        for (int i = 0; i < 4; i++)
#pragma unroll
            for (int j = 0; j < 4; j++)
                acc[i][j] = __builtin_amdgcn_mfma_f32_16x16x32_bf16(af[i], bfr[j], acc[i][j], 0, 0, 0);
        __syncthreads();
    }
#undef QKV_STAGE

#pragma unroll
    for (int j = 0; j < 4; j++) {
        int col = n0 + wn * 64 + j * 16 + l15;     // [0,3072)
        int sel = col >> 10;                        // uniform within 16-col group
        float bvv = (sel == 0) ? bq[col] : (sel == 1) ? bk[col - 1024] : bv[col - 2048];
#pragma unroll
        for (int i = 0; i < 4; i++) {
            int rowb = m0 + wm * 64 + i * 16 + l4 * 4;
            if (sel == 0) {
#pragma unroll
                for (int r = 0; r < 4; r++)
                    Qo[(size_t)(rowb + r) * 1024 + col] = f2bf(acc[i][j][r] + bvv);
            } else if (sel == 1) {
#pragma unroll
                for (int r = 0; r < 4; r++)
                    Ko[(size_t)(rowb + r) * 1024 + (col - 1024)] = f2bf(acc[i][j][r] + bvv);
            } else {
                int cc = col - 2048;
                int bb = rowb >> 11;
                int sp = ((m0 + wm * 64) & 2047) + (i >> 1) * 32 + l4 * 8 + (i & 1) * 4;
                int hh = cc >> 6, dd = cc & 63;
                ushort4 o;
                o.x = f2bf(acc[i][j][0] + bvv);
                o.y = f2bf(acc[i][j][1] + bvv);
                o.z = f2bf(acc[i][j][2] + bvv);
                o.w = f2bf(acc[i][j][3] + bvv);
                *(ushort4*)(Vo + ((size_t)((bb * 16 + hh) * 64 + dd)) * 2048 + sp) = o;
            }
        }
    }
}

// ---------------- output projection GEMM (fp32 out) ----------------
__global__ __launch_bounds__(256, 2) void gemm_o(
        const u16* __restrict__ A, const u16* __restrict__ W,
        const float* __restrict__ bias, float* __restrict__ out) {
    __shared__ __align__(16) u16 As[2][128 * 32];
    __shared__ __align__(16) u16 Bs[2][128 * 32];
    const int tid = threadIdx.x;
    const int lane = tid & 63;
    const int w = tid >> 6, wm = w >> 1, wn = w & 1;
    const int l15 = lane & 15, l4 = lane >> 4;
    int v = (blockIdx.x & 7) * 64 + (blockIdx.x >> 3);   // 512 blocks, 64/XCD
    int vy = v >> 3, vx = v & 7;
    const int m0 = vy * 128, n0 = vx * 128;

    f32x4 acc[4][4];
#pragma unroll
    for (int i = 0; i < 4; i++)
#pragma unroll
        for (int j = 0; j < 4; j++) acc[i][j] = f32x4{0.f, 0.f, 0.f, 0.f};

#define O_STAGE(buf, kt) do {                                              \
    _Pragma("unroll")                                                      \
    for (int i_ = 0; i_ < 2; i_++) {                                       \
        int c_ = tid + i_ * 256;                                           \
        int row_ = c_ >> 2, slot_ = c_ & 3;                                \
        int cc_ = slot_ ^ ((row_ >> 1) & 3);                               \
        GLL16(A + (size_t)(m0 + row_) * 1024 + (kt) + cc_ * 8, As[buf] + c_ * 8); \
    }                                                                      \
    _Pragma("unroll")                                                      \
    for (int i_ = 0; i_ < 2; i_++) {                                       \
        int c_ = tid + i_ * 256;                                           \
        int row_ = c_ >> 2, slot_ = c_ & 3;                                \
        int cc_ = slot_ ^ ((row_ >> 1) & 3);                               \
        GLL16(W + (size_t)(n0 + row_) * 1024 + (kt) + cc_ * 8, Bs[buf] + c_ * 8); \
    }                                                                      \
} while (0)

    O_STAGE(0, 0);
    __syncthreads();

    for (int kt = 0; kt < 1024; kt += 32) {
        const int cur = (kt >> 5) & 1;
        if (kt != 992) O_STAGE(cur ^ 1, kt + 32);

        bf16x8 af[4], bfr[4];
#pragma unroll
        for (int i = 0; i < 4; i++) {
            int row = wm * 64 + i * 16 + l15;
            int slot = l4 ^ ((row >> 1) & 3);
            af[i] = *(const bf16x8*)(As[cur] + row * 32 + slot * 8);
        }
#pragma unroll
        for (int j = 0; j < 4; j++) {
            int row = wn * 64 + j * 16 + l15;
            int slot = l4 ^ ((row >> 1) & 3);
            bfr[j] = *(const bf16x8*)(Bs[cur] + row * 32 + slot * 8);
        }
#pragma unroll
        for (int i = 0; i < 4; i++)
#pragma unroll
            for (int j = 0; j < 4; j++)
                acc[i][j] = __builtin_amdgcn_mfma_f32_16x16x32_bf16(af[i], bfr[j], acc[i][j], 0, 0, 0);
        __syncthreads();
    }
#undef O_STAGE

#pragma unroll
    for (int j = 0; j < 4; j++) {
        int col = n0 + wn * 64 + j * 16 + l15;
        float bvv = bias[col];
#pragma unroll
        for (int i = 0; i < 4; i++) {
            int rowb = m0 + wm * 64 + i * 16 + l4 * 4;
#pragma unroll
            for (int r = 0; r < 4; r++)
                out[(size_t)(rowb + r) * 1024 + col] = acc[i][j][r] + bvv;
        }
    }
}

// ---------------- fused flash attention ----------------
// 1D grid 1024, XCD swizzle: all 16 q-blocks of a (b,h) on one XCD (K/V L2-resident).
// 4 waves x 32 q-rows. S^T = mfma(K,Q); V s-permuted so PV B-operand = lane-local
// P quads (no LDS round-trip). Denominator l computed by PV-side ones-MFMA.
// Block-uniform mask scan selects fast softmax (s2m = fma(p,SC2,-m), no bias/clamp);
// m_run starts at 0, defer-max THR=8 bounds P <= 2^8.
__global__ __launch_bounds__(256, 3) void attn_fused(
        const u16* __restrict__ Q, const u16* __restrict__ K,
        const u16* __restrict__ Vt, const float* __restrict__ mask,
        u16* __restrict__ ctx) {
    __shared__ __align__(16) u16 Ks[2][64 * 64];    // [kv][d], swizzled slots
    __shared__ __align__(16) u16 Vs[2][64 * 64];    // [d][s'], swizzled slots
    __shared__ int mflag[4];

    const int tid = threadIdx.x, lane = tid & 63, w = tid >> 6;
    const int l15 = lane & 15, l4 = lane >> 4;
    const int bid = blockIdx.x;
    const int inner = bid >> 3;
    const int bh = ((inner >> 4) << 3) | (bid & 7);
    const int b = bh >> 4, h = bh & 15;
    const int qw = (inner & 15) * 128 + w * 32;
    const float SC2 = 0.03125f * 1.44269504088896f;  // (1/sqrt(1024)) * log2(e)
    const float THR2 = 8.0f;

    const u16* Qg = Q + (size_t)b * 2048 * 1024 + h * 64;
    const u16* Kg = K + (size_t)b * 2048 * 1024 + h * 64;
    const u16* Vg = Vt + (size_t)bh * 64 * 2048;
    const float* mp = mask + b * 2048;

    // ---- block-uniform mask scan: 256 threads x 8 = 2048 ----
    {
        float4 a = ((const float4*)mp)[tid * 2];
        float4 c = ((const float4*)mp)[tid * 2 + 1];
        bool bad = (a.x == 0.f) | (a.y == 0.f) | (a.z == 0.f) | (a.w == 0.f) |
                   (c.x == 0.f) | (c.y == 0.f) | (c.z == 0.f) | (c.w == 0.f);
        unsigned long long bal = __ballot(bad);
        if (lane == 0) mflag[w] = (bal != 0ull);
    }

    // hoist Q fragments (B-operand layout)
    bf16x8 qfr[2][2];
#pragma unroll
    for (int qi = 0; qi < 2; qi++)
#pragma unroll
        for (int kf = 0; kf < 2; kf++)
            qfr[qi][kf] = *(const bf16x8*)(Qg + (size_t)(qw + qi * 16 + l15) * 1024 + kf * 32 + l4 * 8);

    float mqs[2];
#pragma unroll
    for (int qi = 0; qi < 2; qi++)
        mqs[qi] = (mp[qw + qi * 16 + l15] != 0.f) ? SC2 : 0.f;

    __syncthreads();
    const bool anym = (mflag[0] | mflag[1] | mflag[2] | mflag[3]) != 0;

#define STAGE_KV(buf, kvbase) do {                                         \
    _Pragma("unroll")                                                      \
    for (int i_ = 0; i_ < 2; i_++) {                                       \
        int c_ = tid + i_ * 256;                                           \
        int row_ = c_ >> 3, slot_ = c_ & 7;                                \
        int cc_ = slot_ ^ (row_ & 7);                                      \
        GLL16(Kg + (size_t)((kvbase) + row_) * 1024 + cc_ * 8, Ks[buf] + c_ * 8); \
    }                                                                      \
    _Pragma("unroll")                                                      \
    for (int i_ = 0; i_ < 2; i_++) {                                       \
        int c_ = tid + i_ * 256;                                           \
        int row_ = c_ >> 3, slot_ = c_ & 7;                                \
        int cc_ = slot_ ^ (row_ & 7);                                      \
        GLL16(Vg + (size_t)row_ * 2048 + (kvbase) + cc_ * 8, Vs[buf] + c_ * 8); \
    }                                                                      \
} while (0)

    float m_run[2] = {0.f, 0.f};
    f32x4 acc_l[2];      // denominator via ones-MFMA (all 4 elements equal)
    f32x4 oaccT[4][2];   // O^T: [d-frag][q-frag]
#pragma unroll
    for (int qi = 0; qi < 2; qi++) acc_l[qi] = f32x4{0.f, 0.f, 0.f, 0.f};
#pragma unroll
    for (int df = 0; df < 4; df++)
#pragma unroll
        for (int qi = 0; qi < 2; qi++) oaccT[df][qi] = f32x4{0.f, 0.f, 0.f, 0.f};

    const u32x4 ones4 = u32x4{0x3F803F80u, 0x3F803F80u, 0x3F803F80u, 0x3F803F80u};
    const bf16x8 ones = __builtin_bit_cast(bf16x8, ones4);

    STAGE_KV(0, 0);
    __syncthreads();

    for (int it = 0; it < 32; ++it) {
        const int cur = it & 1;
        const int kv0 = it * 64;

        if (it != 31) STAGE_KV(cur ^ 1, kv0 + 64);

        // ---- S^T = K Q^T ----
        bf16x8 kfr[4][2];
#pragma unroll
        for (int kvf = 0; kvf < 4; kvf++)
#pragma unroll
            for (int kf = 0; kf < 2; kf++) {
                int row = kvf * 16 + l15;
                int slot = (kf * 4 + l4) ^ (row & 7);
                kfr[kvf][kf] = *(const bf16x8*)(Ks[cur] + row * 64 + slot * 8);
            }
        f32x4 p[4][2];
#pragma unroll
        for (int kvf = 0; kvf < 4; kvf++)
#pragma unroll
            for (int qi = 0; qi < 2; qi++) p[kvf][qi] = f32x4{0.f, 0.f, 0.f, 0.f};
        __builtin_amdgcn_s_setprio(1);
#pragma unroll
        for (int kvf = 0; kvf < 4; kvf++)
#pragma unroll
            for (int qi = 0; qi < 2; qi++)
#pragma unroll
                for (int kf = 0; kf < 2; kf++)
                    p[kvf][qi] = __builtin_amdgcn_mfma_f32_16x16x32_bf16(kfr[kvf][kf], qfr[qi][kf], p[kvf][qi], 0, 0, 0);
        __builtin_amdgcn_s_setprio(0);

        // ---- softmax: compute s2m = score*log2e - m_run into p ----
        if (!anym) {
#pragma unroll
            for (int qi = 0; qi < 2; qi++) {
                float mneg = -m_run[qi];
#pragma unroll
                for (int kvf = 0; kvf < 4; kvf++)
#pragma unroll
                    for (int r = 0; r < 4; r++)
                        p[kvf][qi][r] = __builtin_fmaf(p[kvf][qi][r], mqs[qi], mneg);
            }
        } else {
            float4 mkv[4];
#pragma unroll
            for (int kvf = 0; kvf < 4; kvf++)
                mkv[kvf] = ((const float4*)(mp + kv0))[kvf * 4 + l4];
#pragma unroll
            for (int qi = 0; qi < 2; qi++) {
                float mneg = -m_run[qi];
#pragma unroll
                for (int kvf = 0; kvf < 4; kvf++)
#pragma unroll
                    for (int r = 0; r < 4; r++) {
                        float bb = (mkv[kvf][r] != 0.f) ? mneg : -1e12f;
                        p[kvf][qi][r] = __builtin_fmaf(p[kvf][qi][r], mqs[qi], bb);
                    }
            }
        }

        // ---- common: tile max (relative to m_run), defer-max, exp2 ----
        float d2[2];
#pragma unroll
        for (int qi = 0; qi < 2; qi++) {
            float a0 = fmaxf(fmaxf(p[0][qi][0], p[0][qi][1]), fmaxf(p[0][qi][2], p[0][qi][3]));
            float a1 = fmaxf(fmaxf(p[1][qi][0], p[1][qi][1]), fmaxf(p[1][qi][2], p[1][qi][3]));
            float a2 = fmaxf(fmaxf(p[2][qi][0], p[2][qi][1]), fmaxf(p[2][qi][2], p[2][qi][3]));
            float a3 = fmaxf(fmaxf(p[3][qi][0], p[3][qi][1]), fmaxf(p[3][qi][2], p[3][qi][3]));
            float t = fmaxf(fmaxf(a0, a1), fmaxf(a2, a3));
            t = fmaxf(t, __shfl_xor(t, 16));
            t = fmaxf(t, __shfl_xor(t, 32));
            d2[qi] = t;
        }
        if (!__all((d2[0] <= THR2) && (d2[1] <= THR2))) {
#pragma unroll
            for (int qi = 0; qi < 2; qi++) {
                float dd = fmaxf(d2[qi], 0.f);
                float sc = __builtin_amdgcn_exp2f(-dd);
                m_run[qi] += dd;
                acc_l[qi] *= sc;
#pragma unroll
                for (int df = 0; df < 4; df++) oaccT[df][qi] *= sc;
#pragma unroll
                for (int kvf = 0; kvf < 4; kvf++)
#pragma unroll
                    for (int r = 0; r < 4; r++) p[kvf][qi][r] -= dd;
            }
        }
#pragma unroll
        for (int qi = 0; qi < 2; qi++)
#pragma unroll
            for (int kvf = 0; kvf < 4; kvf++)
#pragma unroll
                for (int r = 0; r < 4; r++)
                    p[kvf][qi][r] = __builtin_amdgcn_exp2f(p[kvf][qi][r]);

        // ---- pb = lane-local P quads packed to bf16 ----
        bf16x8 pb[2][2];
#pragma unroll
        for (int qi = 0; qi < 2; qi++)
#pragma unroll
            for (int kf = 0; kf < 2; kf++) {
                u32x4 t;
                t.x = cvtpk(p[2 * kf][qi][0], p[2 * kf][qi][1]);
                t.y = cvtpk(p[2 * kf][qi][2], p[2 * kf][qi][3]);
                t.z = cvtpk(p[2 * kf + 1][qi][0], p[2 * kf + 1][qi][1]);
                t.w = cvtpk(p[2 * kf + 1][qi][2], p[2 * kf + 1][qi][3]);
                pb[qi][kf] = __builtin_bit_cast(bf16x8, t);
            }

        // V fragments after softmax (kept out of the VALU-phase live set)
        bf16x8 vfr[4][2];
#pragma unroll
        for (int df = 0; df < 4; df++)
#pragma unroll
            for (int kf = 0; kf < 2; kf++) {
                int row = df * 16 + l15;
                int slot = (kf * 4 + l4) ^ (row & 7);
                vfr[df][kf] = *(const bf16x8*)(Vs[cur] + row * 64 + slot * 8);
            }

        // ---- O^T += V^T P^T ; l += ones^T P^T ----
        __builtin_amdgcn_s_setprio(1);
#pragma unroll
        for (int df = 0; df < 4; df++)
#pragma unroll
            for (int qi = 0; qi < 2; qi++)
#pragma unroll
                for (int kf = 0; kf < 2; kf++)
                    oaccT[df][qi] = __builtin_amdgcn_mfma_f32_16x16x32_bf16(vfr[df][kf], pb[qi][kf], oaccT[df][qi], 0, 0, 0);
#pragma unroll
        for (int qi = 0; qi < 2; qi++)
#pragma unroll
            for (int kf = 0; kf < 2; kf++)
                acc_l[qi] = __builtin_amdgcn_mfma_f32_16x16x32_bf16(ones, pb[qi][kf], acc_l[qi], 0, 0, 0);
        __builtin_amdgcn_s_setprio(0);

        __syncthreads();   // drains prefetch vmcnt + protects both dbuf halves
    }

    // ---- epilogue: ctx[token][h*64+d] = O^T / l ----
#pragma unroll
    for (int qi = 0; qi < 2; qi++) {
        float rl = 1.0f / acc_l[qi][0];
        int tok = qw + qi * 16 + l15;
#pragma unroll
        for (int df = 0; df < 4; df++) {
            uint2 o;
            o.x = cvtpk(oaccT[df][qi][0] * rl, oaccT[df][qi][1] * rl);
            o.y = cvtpk(oaccT[df][qi][2] * rl, oaccT[df][qi][3] * rl);
            *(uint2*)(ctx + (size_t)(b * 2048 + tok) * 1024 + h * 64 + df * 16 + l4 * 4) = o;
        }
    }
#undef STAGE_KV
}

extern "C" void kernel_launch(void* const* d_in, const int* in_sizes, int n_in,
                              void* d_out, int out_size, void* d_ws, size_t ws_size,
                              hipStream_t stream) {
    const float* hs    = (const float*)d_in[0];
    const float* masks = (const float*)d_in[1];
    const float* Wq = (const float*)d_in[2];
    const float* bq = (const float*)d_in[3];
    const float* Wk = (const float*)d_in[4];
    const float* bk = (const float*)d_in[5];
    const float* Wv = (const float*)d_in[6];
    const float* bv = (const float*)d_in[7];
    const float* Wo = (const float*)d_in[8];
    const float* bo = (const float*)d_in[9];

    const int NT = 4 * 2048;   // 8192 tokens
    const int H = 1024;

    u16* hs_b = (u16*)d_ws;                       // [8192,1024]
    u16* w_b  = hs_b + (size_t)NT * H;            // [Wq|Wk|Wv|Wo] 4x[1024,1024]
    u16* wo_b = w_b + (size_t)3 * H * H;
    u16* Qb   = w_b + (size_t)4 * H * H;          // [8192,1024]
    u16* Kb   = Qb + (size_t)NT * H;              // [8192,1024]
    u16* Vtb  = Kb + (size_t)NT * H;              // [64][64][2048] s-permuted
    u16* Cb   = hs_b;                             // attn output reuses hidden buffer

    cvt_f32_bf16<<<NT * H / 1024, 256, 0, stream>>>(hs, hs_b, NT * H / 4);
    cvt_w4<<<dim3(H * H / 1024, 4), 256, 0, stream>>>(Wq, Wk, Wv, Wo, w_b);

    gemm_qkv<<<1536, 256, 0, stream>>>(hs_b, w_b, bq, bk, bv, Qb, Kb, Vtb);

    attn_fused<<<1024, 256, 0, stream>>>(Qb, Kb, Vtb, masks, Cb);

    gemm_o<<<512, 256, 0, stream>>>(Cb, wo_b, bo, (float*)d_out);
}